// Round 1
// baseline (3098.911 us; speedup 1.0000x reference)
//
#include <hip/hip_runtime.h>
#include <hip/hip_bf16.h>
#include <math.h>

// ---------------------------------------------------------------------------
// MLA forward, fp32 correctness-first baseline.
// B=2 S=2048 H=2048 nh=16 hd=128 rd=64 L=256  (all dims hard-coded)
// ---------------------------------------------------------------------------

// Generic fp32 GEMM: C[M,N] = A[M,K] @ B[K,N], all row-major.
// 64x64 tile, BK=16, 256 threads, 4x4 micro-tile per thread.
__global__ __launch_bounds__(256) void gemm_f32(const float* __restrict__ A,
                                                const float* __restrict__ B,
                                                float* __restrict__ C,
                                                int M, int N, int K) {
  __shared__ float As[16][64];  // As[k][m]
  __shared__ float Bs[16][64];  // Bs[k][n]
  const int tid = threadIdx.x;
  const int tx = tid & 15, ty = tid >> 4;
  const int row0 = blockIdx.y * 64, col0 = blockIdx.x * 64;
  const int a_k = tid & 15, a_m = tid >> 4;   // A loader: 16 k-cols x 16 rows (x4)
  const int b_n = tid & 63, b_k = tid >> 6;   // B loader: 64 n-cols x 4 k-rows (x4)
  float acc[4][4] = {};
  for (int k0 = 0; k0 < K; k0 += 16) {
#pragma unroll
    for (int i = 0; i < 4; ++i)
      As[a_k][a_m + 16 * i] = A[(row0 + a_m + 16 * i) * K + k0 + a_k];
#pragma unroll
    for (int i = 0; i < 4; ++i)
      Bs[b_k + 4 * i][b_n] = B[(k0 + b_k + 4 * i) * N + col0 + b_n];
    __syncthreads();
#pragma unroll
    for (int kk = 0; kk < 16; ++kk) {
      float a[4], b[4];
#pragma unroll
      for (int i = 0; i < 4; ++i) a[i] = As[kk][ty * 4 + i];
#pragma unroll
      for (int j = 0; j < 4; ++j) b[j] = Bs[kk][tx * 4 + j];
#pragma unroll
      for (int i = 0; i < 4; ++i)
#pragma unroll
        for (int j = 0; j < 4; ++j) acc[i][j] = fmaf(a[i], b[j], acc[i][j]);
    }
    __syncthreads();
  }
#pragma unroll
  for (int i = 0; i < 4; ++i)
#pragma unroll
    for (int j = 0; j < 4; ++j)
      C[(row0 + ty * 4 + i) * N + col0 + tx * 4 + j] = acc[i][j];
}

// RoPE + concat + pack: builds q_full/k_full, layout (B*S, nh*128) where
// cols [h*128, h*128+64) = *_c and [h*128+64, h*128+128) = roped *_r.
__global__ __launch_bounds__(256) void rope_concat(
    const float* __restrict__ qc, const float* __restrict__ qr,
    const float* __restrict__ kc, const float* __restrict__ kr,
    float* __restrict__ qf, float* __restrict__ kf) {
  int idx = blockIdx.x * 256 + threadIdx.x;  // over 4096*2048
  int m = idx >> 11;        // row in [0,4096)
  int col = idx & 2047;
  int h = col >> 7;         // head
  int j = col & 127;        // dim within head
  int s = m & 2047;         // sequence position (S=2048, pow2)
  float oq, ok;
  if (j < 64) {
    int src = m * 1024 + h * 64 + j;
    oq = qc[src];
    ok = kc[src];
  } else {
    int jr = j - 64;
    int f = jr & 31;
    // inv_freq[f] = 10000^(-2f/64) = exp(-f * ln(10000)/32)
    float ang = (float)s * expf(-0.2878231366242557f * (float)f);
    float c = cosf(ang), sn = sinf(ang);
    int base = m * 1024 + h * 64;
    float xq = qr[base + jr], xk = kr[base + jr];
    float rq, rk;
    if (jr < 32) { rq = -qr[base + jr + 32]; rk = -kr[base + jr + 32]; }
    else         { rq =  qr[base + jr - 32]; rk =  kr[base + jr - 32]; }
    oq = fmaf(xq, c, rq * sn);
    ok = fmaf(xk, c, rk * sn);
  }
  int dst = m * 2048 + h * 128 + j;
  qf[dst] = oq;
  kf[dst] = ok;
}

// Flash-style causal attention. Q/K tiles of 32 rows, d=128.
// Grid: (S/32, nh, B). 256 threads: tx=tid&15 (k-cols*2), ty=tid>>4 (q-rows*2).
// Output y in (B,S,nh,hd) = (4096, 2048) row-major.
__global__ __launch_bounds__(256) void flash_attn(const float* __restrict__ qf,
                                                  const float* __restrict__ kf,
                                                  const float* __restrict__ vv,
                                                  float* __restrict__ y) {
  __shared__ float Qs[32 * 129];
  __shared__ float Ks[32 * 129];
  __shared__ float Vs[32 * 129];
  __shared__ float Ps[32 * 33];
  const int qt = blockIdx.x;   // 0..63
  const int h = blockIdx.y;    // 0..15
  const int b = blockIdx.z;    // 0..1
  const int tid = threadIdx.x;
  const int tx = tid & 15, ty = tid >> 4;
  const int q0 = qt * 32;
  const int base = b * 2048 * 2048 + h * 128;  // element offset into (4096,2048)
  const float scale = 0.08838834764831845f;    // 1/sqrt(128)

  for (int idx = tid; idx < 32 * 128; idx += 256) {
    int r = idx >> 7, c = idx & 127;
    Qs[r * 129 + c] = qf[base + (q0 + r) * 2048 + c];
  }
  float m_i[2] = {-INFINITY, -INFINITY};
  float l_i[2] = {0.f, 0.f};
  float o[2][8] = {};

  for (int kt = 0; kt <= qt; ++kt) {
    const int k0 = kt * 32;
    __syncthreads();  // prev PV done (and Qs load on first iter)
    for (int idx = tid; idx < 32 * 128; idx += 256) {
      int r = idx >> 7, c = idx & 127;
      Ks[r * 129 + c] = kf[base + (k0 + r) * 2048 + c];
      Vs[r * 129 + c] = vv[base + (k0 + r) * 2048 + c];
    }
    __syncthreads();

    float sc[2][2] = {};
    for (int d = 0; d < 128; ++d) {
      float a0 = Qs[(ty * 2 + 0) * 129 + d];
      float a1 = Qs[(ty * 2 + 1) * 129 + d];
      float b0 = Ks[(tx * 2 + 0) * 129 + d];
      float b1 = Ks[(tx * 2 + 1) * 129 + d];
      sc[0][0] = fmaf(a0, b0, sc[0][0]);
      sc[0][1] = fmaf(a0, b1, sc[0][1]);
      sc[1][0] = fmaf(a1, b0, sc[1][0]);
      sc[1][1] = fmaf(a1, b1, sc[1][1]);
    }
    const bool diag = (kt == qt);
#pragma unroll
    for (int i = 0; i < 2; ++i)
#pragma unroll
      for (int j = 0; j < 2; ++j) {
        float sv = sc[i][j] * scale;
        if (diag && (k0 + tx * 2 + j) > (q0 + ty * 2 + i)) sv = -INFINITY;
        sc[i][j] = sv;
      }
#pragma unroll
    for (int i = 0; i < 2; ++i) {
      float mt = fmaxf(sc[i][0], sc[i][1]);
#pragma unroll
      for (int off = 1; off < 16; off <<= 1)
        mt = fmaxf(mt, __shfl_xor(mt, off, 16));
      float mnew = fmaxf(m_i[i], mt);
      float alpha = expf(m_i[i] - mnew);  // first tile: expf(-inf)=0, mnew finite
      float p0 = expf(sc[i][0] - mnew);
      float p1 = expf(sc[i][1] - mnew);
      Ps[(ty * 2 + i) * 33 + tx * 2 + 0] = p0;
      Ps[(ty * 2 + i) * 33 + tx * 2 + 1] = p1;
      float psum = p0 + p1;
#pragma unroll
      for (int off = 1; off < 16; off <<= 1)
        psum += __shfl_xor(psum, off, 16);
      l_i[i] = l_i[i] * alpha + psum;
      m_i[i] = mnew;
#pragma unroll
      for (int cc = 0; cc < 8; ++cc) o[i][cc] *= alpha;
    }
    __syncthreads();  // Ps visible before PV
    for (int c = 0; c < 32; ++c) {
      float p0 = Ps[(ty * 2 + 0) * 33 + c];
      float p1 = Ps[(ty * 2 + 1) * 33 + c];
#pragma unroll
      for (int cc = 0; cc < 8; ++cc) {
        float vval = Vs[c * 129 + tx + 16 * cc];
        o[0][cc] = fmaf(p0, vval, o[0][cc]);
        o[1][cc] = fmaf(p1, vval, o[1][cc]);
      }
    }
  }
#pragma unroll
  for (int i = 0; i < 2; ++i) {
    float inv = 1.0f / l_i[i];
    int rbase = base + (q0 + ty * 2 + i) * 2048 + tx;
#pragma unroll
    for (int cc = 0; cc < 8; ++cc) y[rbase + 16 * cc] = o[i][cc] * inv;
  }
}

extern "C" void kernel_launch(void* const* d_in, const int* in_sizes, int n_in,
                              void* d_out, int out_size, void* d_ws, size_t ws_size,
                              hipStream_t stream) {
  const float* hs   = (const float*)d_in[0];  // (4096, 2048)
  const float* Wkvd = (const float*)d_in[1];  // (2048, 256)
  const float* Wqd  = (const float*)d_in[2];  // (2048, 256)
  const float* Wku  = (const float*)d_in[3];  // (256, 1024)
  const float* Wqu  = (const float*)d_in[4];  // (256, 1024)
  const float* Wvu  = (const float*)d_in[5];  // (256, 2048)
  const float* Wrk  = (const float*)d_in[6];  // (2048, 1024)
  const float* Wrq  = (const float*)d_in[7];  // (256, 1024)
  const float* Wo   = (const float*)d_in[8];  // (2048, 2048)
  float* out = (float*)d_out;                 // (4096, 2048) fp32
  char* ws = (char*)d_ws;

  const size_t MB = 1024ull * 1024ull;
  // Workspace layout (168 MB total). y reuses [0,32MB): kv_d/q_d/k_c/q_c
  // are dead by the time attention runs.
  float* kv_d = (float*)(ws + 0 * MB);    // 4096x256   (4 MB)
  float* q_d  = (float*)(ws + 4 * MB);    // 4096x256   (4 MB)
  float* k_c  = (float*)(ws + 8 * MB);    // 4096x1024  (16 MB)
  float* q_c  = (float*)(ws + 24 * MB);   // 4096x1024  (16 MB)
  float* k_r  = (float*)(ws + 40 * MB);   // 4096x1024  (16 MB)
  float* q_r  = (float*)(ws + 56 * MB);   // 4096x1024  (16 MB)
  float* v    = (float*)(ws + 72 * MB);   // 4096x2048  (32 MB)
  float* q_f  = (float*)(ws + 104 * MB);  // 4096x2048  (32 MB)
  float* k_f  = (float*)(ws + 136 * MB);  // 4096x2048  (32 MB)
  float* y    = (float*)(ws + 0 * MB);    // 4096x2048  (32 MB, reuse)

  dim3 blk(256);
  // Down/up projections
  gemm_f32<<<dim3(4, 64),  blk, 0, stream>>>(hs,   Wkvd, kv_d, 4096, 256,  2048);
  gemm_f32<<<dim3(4, 64),  blk, 0, stream>>>(hs,   Wqd,  q_d,  4096, 256,  2048);
  gemm_f32<<<dim3(16, 64), blk, 0, stream>>>(hs,   Wrk,  k_r,  4096, 1024, 2048);
  gemm_f32<<<dim3(16, 64), blk, 0, stream>>>(kv_d, Wku,  k_c,  4096, 1024, 256);
  gemm_f32<<<dim3(32, 64), blk, 0, stream>>>(kv_d, Wvu,  v,    4096, 2048, 256);
  gemm_f32<<<dim3(16, 64), blk, 0, stream>>>(q_d,  Wqu,  q_c,  4096, 1024, 256);
  gemm_f32<<<dim3(16, 64), blk, 0, stream>>>(q_d,  Wrq,  q_r,  4096, 1024, 256);
  // RoPE + concat into attention-ready layout
  rope_concat<<<dim3(32768), blk, 0, stream>>>(q_c, q_r, k_c, k_r, q_f, k_f);
  // Flash causal attention -> y (B,S,nh,hd) == (4096,2048)
  flash_attn<<<dim3(64, 16, 2), blk, 0, stream>>>(q_f, k_f, v, y);
  // Output projection
  gemm_f32<<<dim3(32, 64), blk, 0, stream>>>(y, Wo, out, 4096, 2048, 2048);
}

// Round 2
// 601.053 us; speedup vs baseline: 5.1558x; 5.1558x over previous
//
#include <hip/hip_runtime.h>
#include <hip/hip_bf16.h>
#include <math.h>

// ---------------------------------------------------------------------------
// MLA forward, bf16 MFMA version.
// B=2 S=2048 H=2048 nh=16 hd=128 rd=64 L=256
// MFMA 16x16x32 bf16: A-frag lane holds A[m=lane&15][k=quad*8+j]
//                     B-frag lane holds Bt[n=lane&15][k=quad*8+j]  (Bt = B^T)
//                     C/D: col=lane&15, row=quad*4+reg
// ---------------------------------------------------------------------------

typedef __attribute__((ext_vector_type(8))) short bf16x8;
typedef __attribute__((ext_vector_type(4))) float f32x4;

#define MFMA16(a, b, c) __builtin_amdgcn_mfma_f32_16x16x32_bf16(a, b, c, 0, 0, 0)

__device__ inline short f2bs(float f) {
  __hip_bfloat16 h = __float2bfloat16(f);
  return *reinterpret_cast<short*>(&h);
}
__device__ inline float bs2f(short s) {
  union { unsigned int u; float f; } v;
  v.u = ((unsigned int)(unsigned short)s) << 16;
  return v.f;
}

// ---------------- cast fp32 -> bf16 (hs) ----------------
__global__ __launch_bounds__(256) void castf2b(const float* __restrict__ x,
                                               short* __restrict__ y) {
  int i = (blockIdx.x * 256 + threadIdx.x) * 4;
  float4 v = *(const float4*)(x + i);
  short4 o;
  o.x = f2bs(v.x); o.y = f2bs(v.y); o.z = f2bs(v.z); o.w = f2bs(v.w);
  *(short4*)(y + i) = o;
}

// ---------------- transpose + cast weights: W(K,N) f32 -> Wt(N,K) bf16 -----
__global__ __launch_bounds__(256) void wtrans(const float* __restrict__ W,
                                              short* __restrict__ Wt,
                                              int K, int N) {
  __shared__ float t[32][33];
  int k0 = blockIdx.y * 32, n0 = blockIdx.x * 32;
#pragma unroll
  for (int i = 0; i < 4; ++i) {
    int idx = threadIdx.x + i * 256;
    int r = idx >> 5, c = idx & 31;
    t[r][c] = W[(k0 + r) * N + n0 + c];
  }
  __syncthreads();
#pragma unroll
  for (int i = 0; i < 4; ++i) {
    int idx = threadIdx.x + i * 256;
    int r = idx >> 5, c = idx & 31;
    Wt[(n0 + r) * (size_t)K + k0 + c] = f2bs(t[c][r]);
  }
}

// ---------------- bf16 MFMA GEMM: C[M,N] = A[M,K] @ Bt[N,K]^T --------------
__device__ inline void cstore(float v, float* p) { *p = v; }
__device__ inline void cstore(float v, short* p) { *p = f2bs(v); }

template <typename CT>
__global__ __launch_bounds__(256) void gemm_bt(const short* __restrict__ A,
                                               const short* __restrict__ Bt,
                                               CT* __restrict__ C,
                                               int M, int N, int K) {
  __shared__ short As[128 * 32];
  __shared__ short Bs[128 * 32];
  const int tid = threadIdx.x;
  const int wave = tid >> 6, lane = tid & 63;
  const int quad = lane >> 4, l15 = lane & 15;
  const int wm = wave & 1, wn = wave >> 1;
  const int row0 = blockIdx.y * 128, col0 = blockIdx.x * 128;

  f32x4 acc[4][4];
#pragma unroll
  for (int i = 0; i < 4; ++i)
#pragma unroll
    for (int j = 0; j < 4; ++j) acc[i][j] = {0.f, 0.f, 0.f, 0.f};

  for (int k0 = 0; k0 < K; k0 += 32) {
    __syncthreads();
#pragma unroll
    for (int i = 0; i < 2; ++i) {
      int idx = tid + i * 256;
      int r = idx >> 2, lc = idx & 3;
      int sw = (lc ^ r ^ (r >> 2)) & 3;
      *(bf16x8*)&As[r * 32 + sw * 8] =
          *(const bf16x8*)&A[(size_t)(row0 + r) * K + k0 + lc * 8];
      *(bf16x8*)&Bs[r * 32 + sw * 8] =
          *(const bf16x8*)&Bt[(size_t)(col0 + r) * K + k0 + lc * 8];
    }
    __syncthreads();
    bf16x8 af[4], bfr[4];
#pragma unroll
    for (int i = 0; i < 4; ++i) {
      int ar = wm * 64 + i * 16 + l15;
      af[i] = *(const bf16x8*)&As[ar * 32 + ((quad ^ ar ^ (ar >> 2)) & 3) * 8];
      int br = wn * 64 + i * 16 + l15;
      bfr[i] = *(const bf16x8*)&Bs[br * 32 + ((quad ^ br ^ (br >> 2)) & 3) * 8];
    }
#pragma unroll
    for (int i = 0; i < 4; ++i)
#pragma unroll
      for (int j = 0; j < 4; ++j)
        acc[i][j] = MFMA16(af[i], bfr[j], acc[i][j]);
  }
#pragma unroll
  for (int i = 0; i < 4; ++i)
#pragma unroll
    for (int j = 0; j < 4; ++j)
#pragma unroll
      for (int r = 0; r < 4; ++r) {
        int row = row0 + wm * 64 + i * 16 + quad * 4 + r;
        int col = col0 + wn * 64 + j * 16 + l15;
        cstore(acc[i][j][r], &C[(size_t)row * N + col]);
      }
}

// ---------------- RoPE + concat + head-major pack (bf16) -------------------
// outputs q_f, k_f: (b, h, s, 128)
__global__ __launch_bounds__(256) void rope_pack(
    const short* __restrict__ qc, const short* __restrict__ qr,
    const short* __restrict__ kc, const short* __restrict__ kr,
    short* __restrict__ qf, short* __restrict__ kf) {
  int idx = blockIdx.x * 256 + threadIdx.x;  // over 4096*2048
  int m = idx >> 11;
  int col = idx & 2047;
  int h = col >> 7;
  int j = col & 127;
  int b = m >> 11, s = m & 2047;
  float oq, ok;
  if (j < 64) {
    int src = m * 1024 + h * 64 + j;
    oq = bs2f(qc[src]);
    ok = bs2f(kc[src]);
  } else {
    int jr = j - 64;
    int f = jr & 31;
    float ang = (float)s * __expf(-0.2878231366242557f * (float)f);
    float c = __cosf(ang), sn = __sinf(ang);
    int base = m * 1024 + h * 64;
    float xq = bs2f(qr[base + jr]), xk = bs2f(kr[base + jr]);
    float rq, rk;
    if (jr < 32) { rq = -bs2f(qr[base + jr + 32]); rk = -bs2f(kr[base + jr + 32]); }
    else         { rq =  bs2f(qr[base + jr - 32]); rk =  bs2f(kr[base + jr - 32]); }
    oq = fmaf(xq, c, rq * sn);
    ok = fmaf(xk, c, rk * sn);
  }
  size_t dst = (((size_t)b * 16 + h) * 2048 + s) * 128 + j;
  qf[dst] = f2bs(oq);
  kf[dst] = f2bs(ok);
}

// ---------------- V transpose: v(b*s, h*128) -> vt(b,h,128,s) --------------
__global__ __launch_bounds__(256) void vtrans(const short* __restrict__ v,
                                              short* __restrict__ vt) {
  __shared__ short t[64][72];
  int s0 = blockIdx.x * 64, d0 = blockIdx.y * 64, bh = blockIdx.z;
  int b = bh >> 4, h = bh & 15;
#pragma unroll
  for (int i = 0; i < 16; ++i) {
    int idx = threadIdx.x + i * 256;
    int r = idx >> 6, c = idx & 63;
    t[r][c] = v[(size_t)(b * 2048 + s0 + r) * 2048 + h * 128 + d0 + c];
  }
  __syncthreads();
#pragma unroll
  for (int i = 0; i < 16; ++i) {
    int idx = threadIdx.x + i * 256;
    int r = idx >> 6, c = idx & 63;
    vt[((size_t)bh * 128 + d0 + r) * 2048 + s0 + c] = t[c][r];
  }
}

// ---------------- MFMA flash attention ------------------------------------
// grid (16 q-tiles of 128 rows, 32 bh). 256 threads = 4 waves, 32 q-rows/wave.
__global__ __launch_bounds__(256) void attn_mfma(const short* __restrict__ qf,
                                                 const short* __restrict__ kf,
                                                 const short* __restrict__ vt,
                                                 short* __restrict__ y) {
  __shared__ short Ks[64 * 128];     // 64 kpos x 128 d (swizzled 16B chunks)
  __shared__ short Vs[128 * 64];     // 128 d x 64 kpos (swizzled)
  __shared__ short Ps[4][32 * 64];   // per-wave P tile (swizzled)
  const int qt = blockIdx.x;
  const int bh = blockIdx.y;
  const int tid = threadIdx.x;
  const int wave = tid >> 6, lane = tid & 63;
  const int quad = lane >> 4, l15 = lane & 15;
  const int q0 = qt * 128 + wave * 32;
  const float scale = 0.08838834764831845f;  // 1/sqrt(128)

  // Q fragments [mi][kc] straight from global
  bf16x8 qfr[2][4];
#pragma unroll
  for (int mi = 0; mi < 2; ++mi) {
    const short* qp = qf + (((size_t)bh * 2048) + q0 + mi * 16 + l15) * 128;
#pragma unroll
    for (int kc = 0; kc < 4; ++kc)
      qfr[mi][kc] = *(const bf16x8*)(qp + kc * 32 + quad * 8);
  }

  float m_i[2][4], l_i[2][4];
  f32x4 O[2][8];
#pragma unroll
  for (int mi = 0; mi < 2; ++mi) {
#pragma unroll
    for (int r = 0; r < 4; ++r) { m_i[mi][r] = -INFINITY; l_i[mi][r] = 0.f; }
#pragma unroll
    for (int dt = 0; dt < 8; ++dt) O[mi][dt] = {0.f, 0.f, 0.f, 0.f};
  }

  const int nkt = 2 * qt + 2;
  for (int kt = 0; kt < nkt; ++kt) {
    const int k0 = kt * 64;
    __syncthreads();
#pragma unroll
    for (int i = 0; i < 4; ++i) {
      int idx = tid + i * 256;
      int r = idx >> 4, lc = idx & 15;
      *(bf16x8*)&Ks[r * 128 + ((lc ^ r) & 15) * 8] =
          *(const bf16x8*)(kf + (((size_t)bh * 2048) + k0 + r) * 128 + lc * 8);
      int rv = idx >> 3, lv = idx & 7;
      *(bf16x8*)&Vs[rv * 64 + ((lv ^ rv) & 7) * 8] =
          *(const bf16x8*)(vt + ((size_t)bh * 128 + rv) * 2048 + k0 + lv * 8);
    }
    __syncthreads();

    // S = Q @ K^T  (per wave: 32 x 64)
    f32x4 S[2][4];
#pragma unroll
    for (int mi = 0; mi < 2; ++mi)
#pragma unroll
      for (int j = 0; j < 4; ++j) S[mi][j] = {0.f, 0.f, 0.f, 0.f};
#pragma unroll
    for (int kc = 0; kc < 4; ++kc) {
      bf16x8 kb[4];
#pragma unroll
      for (int j = 0; j < 4; ++j) {
        int krow = j * 16 + l15;
        int cc = kc * 4 + quad;
        kb[j] = *(const bf16x8*)&Ks[krow * 128 + ((cc ^ krow) & 15) * 8];
      }
#pragma unroll
      for (int mi = 0; mi < 2; ++mi)
#pragma unroll
        for (int j = 0; j < 4; ++j)
          S[mi][j] = MFMA16(qfr[mi][kc], kb[j], S[mi][j]);
    }

    // online softmax + write P (bf16) into per-wave LDS
    const bool diag = (kt >= 2 * qt);
#pragma unroll
    for (int mi = 0; mi < 2; ++mi) {
      int rowb = q0 + mi * 16 + quad * 4;
#pragma unroll
      for (int r = 0; r < 4; ++r) {
        float sv[4];
#pragma unroll
        for (int j = 0; j < 4; ++j) {
          float x = S[mi][j][r] * scale;
          if (diag && (k0 + j * 16 + l15) > (rowb + r)) x = -INFINITY;
          sv[j] = x;
        }
        float mt = fmaxf(fmaxf(sv[0], sv[1]), fmaxf(sv[2], sv[3]));
#pragma unroll
        for (int off = 1; off < 16; off <<= 1)
          mt = fmaxf(mt, __shfl_xor(mt, off, 16));
        float mold = m_i[mi][r];
        float mnew = fmaxf(mold, mt);
        float alpha = __expf(mold - mnew);
        float psum = 0.f;
        int prow = mi * 16 + quad * 4 + r;
#pragma unroll
        for (int j = 0; j < 4; ++j) {
          float p = __expf(sv[j] - mnew);
          psum += p;
          int pcol = j * 16 + l15;
          Ps[wave][prow * 64 + (((pcol >> 3) ^ prow) & 7) * 8 + (pcol & 7)] =
              f2bs(p);
        }
#pragma unroll
        for (int off = 1; off < 16; off <<= 1)
          psum += __shfl_xor(psum, off, 16);
        m_i[mi][r] = mnew;
        l_i[mi][r] = l_i[mi][r] * alpha + psum;
#pragma unroll
        for (int dt = 0; dt < 8; ++dt) O[mi][dt][r] *= alpha;
      }
    }
    __syncthreads();  // order Ps writes before A-frag reads (uniform flow)

    // O += P @ V
#pragma unroll
    for (int kc2 = 0; kc2 < 2; ++kc2) {
      bf16x8 pa[2];
#pragma unroll
      for (int mi = 0; mi < 2; ++mi) {
        int prow = mi * 16 + l15;
        int cc = kc2 * 4 + quad;
        pa[mi] = *(const bf16x8*)&Ps[wave][prow * 64 + ((cc ^ prow) & 7) * 8];
      }
#pragma unroll
      for (int dt = 0; dt < 8; ++dt) {
        int vrow = dt * 16 + l15;
        int cc = kc2 * 4 + quad;
        bf16x8 vb = *(const bf16x8*)&Vs[vrow * 64 + ((cc ^ vrow) & 7) * 8];
#pragma unroll
        for (int mi = 0; mi < 2; ++mi)
          O[mi][dt] = MFMA16(pa[mi], vb, O[mi][dt]);
      }
    }
  }

  // epilogue: y (b, s, h, d) bf16
  const int b = bh >> 4, h = bh & 15;
#pragma unroll
  for (int mi = 0; mi < 2; ++mi)
#pragma unroll
    for (int r = 0; r < 4; ++r) {
      float inv = 1.f / l_i[mi][r];
      int row = q0 + mi * 16 + quad * 4 + r;
      size_t base = (((size_t)b * 2048 + row) * 16 + h) * 128;
#pragma unroll
      for (int dt = 0; dt < 8; ++dt)
        y[base + dt * 16 + l15] = f2bs(O[mi][dt][r] * inv);
    }
}

extern "C" void kernel_launch(void* const* d_in, const int* in_sizes, int n_in,
                              void* d_out, int out_size, void* d_ws, size_t ws_size,
                              hipStream_t stream) {
  const float* hs   = (const float*)d_in[0];  // (4096, 2048)
  const float* Wkvd = (const float*)d_in[1];  // (2048, 256)
  const float* Wqd  = (const float*)d_in[2];  // (2048, 256)
  const float* Wku  = (const float*)d_in[3];  // (256, 1024)
  const float* Wqu  = (const float*)d_in[4];  // (256, 1024)
  const float* Wvu  = (const float*)d_in[5];  // (256, 2048)
  const float* Wrk  = (const float*)d_in[6];  // (2048, 1024)
  const float* Wrq  = (const float*)d_in[7];  // (256, 1024)
  const float* Wo   = (const float*)d_in[8];  // (2048, 2048)
  float* out = (float*)d_out;
  char* ws = (char*)d_ws;
  const size_t MB = 1024ull * 1024ull;

  short* hs_b    = (short*)(ws + 0 * MB);    // 16 MB
  short* Wkvd_t  = (short*)(ws + 16 * MB);   // 1 MB  (256,2048)
  short* Wqd_t   = (short*)(ws + 17 * MB);   // 1 MB
  short* Wku_t   = (short*)(ws + 18 * MB);   // 0.5 MB (1024,256)
  short* Wqu_t   = (short*)(ws + 19 * MB);   // 0.5 MB
  short* Wvu_t   = (short*)(ws + 20 * MB);   // 1 MB  (2048,256)
  short* Wrk_t   = (short*)(ws + 21 * MB);   // 4 MB  (1024,2048)
  short* Wrq_t   = (short*)(ws + 25 * MB);   // 0.5 MB
  short* Wo_t    = (short*)(ws + 26 * MB);   // 8 MB  (2048,2048)
  short* kv_d_b  = (short*)(ws + 34 * MB);   // 2 MB (4096,256)
  short* q_d_b   = (short*)(ws + 36 * MB);   // 2 MB
  short* k_c_b   = (short*)(ws + 38 * MB);   // 8 MB (4096,1024)
  short* q_c_b   = (short*)(ws + 46 * MB);   // 8 MB
  short* k_r_b   = (short*)(ws + 54 * MB);   // 8 MB
  short* q_r_b   = (short*)(ws + 62 * MB);   // 8 MB
  short* v_b     = (short*)(ws + 70 * MB);   // 16 MB (4096,2048)
  short* q_f     = (short*)(ws + 86 * MB);   // 16 MB (b,h,s,128)
  short* k_f     = (short*)(ws + 102 * MB);  // 16 MB
  short* v_t     = (short*)(ws + 118 * MB);  // 16 MB (b,h,128,s)
  short* y_b     = (short*)(ws + 134 * MB);  // 16 MB (b,s,h,d)

  dim3 blk(256);
  castf2b<<<dim3(8192), blk, 0, stream>>>(hs, hs_b);
  wtrans<<<dim3(8, 64),  blk, 0, stream>>>(Wkvd, Wkvd_t, 2048, 256);
  wtrans<<<dim3(8, 64),  blk, 0, stream>>>(Wqd,  Wqd_t,  2048, 256);
  wtrans<<<dim3(32, 8),  blk, 0, stream>>>(Wku,  Wku_t,  256, 1024);
  wtrans<<<dim3(32, 8),  blk, 0, stream>>>(Wqu,  Wqu_t,  256, 1024);
  wtrans<<<dim3(64, 8),  blk, 0, stream>>>(Wvu,  Wvu_t,  256, 2048);
  wtrans<<<dim3(32, 64), blk, 0, stream>>>(Wrk,  Wrk_t,  2048, 1024);
  wtrans<<<dim3(32, 8),  blk, 0, stream>>>(Wrq,  Wrq_t,  256, 1024);
  wtrans<<<dim3(64, 64), blk, 0, stream>>>(Wo,   Wo_t,   2048, 2048);

  gemm_bt<short><<<dim3(2, 32),  blk, 0, stream>>>(hs_b,   Wkvd_t, kv_d_b, 4096, 256,  2048);
  gemm_bt<short><<<dim3(2, 32),  blk, 0, stream>>>(hs_b,   Wqd_t,  q_d_b,  4096, 256,  2048);
  gemm_bt<short><<<dim3(8, 32),  blk, 0, stream>>>(hs_b,   Wrk_t,  k_r_b,  4096, 1024, 2048);
  gemm_bt<short><<<dim3(8, 32),  blk, 0, stream>>>(kv_d_b, Wku_t,  k_c_b,  4096, 1024, 256);
  gemm_bt<short><<<dim3(16, 32), blk, 0, stream>>>(kv_d_b, Wvu_t,  v_b,    4096, 2048, 256);
  gemm_bt<short><<<dim3(8, 32),  blk, 0, stream>>>(q_d_b,  Wqu_t,  q_c_b,  4096, 1024, 256);
  gemm_bt<short><<<dim3(8, 32),  blk, 0, stream>>>(q_d_b,  Wrq_t,  q_r_b,  4096, 1024, 256);

  rope_pack<<<dim3(32768), blk, 0, stream>>>(q_c_b, q_r_b, k_c_b, k_r_b, q_f, k_f);
  vtrans<<<dim3(32, 2, 32), blk, 0, stream>>>(v_b, v_t);

  attn_mfma<<<dim3(16, 32), blk, 0, stream>>>(q_f, k_f, v_t, y_b);

  gemm_bt<float><<<dim3(16, 32), blk, 0, stream>>>(y_b, Wo_t, out, 4096, 2048, 2048);
}

// Round 3
// 446.035 us; speedup vs baseline: 6.9477x; 1.3475x over previous
//
#include <hip/hip_runtime.h>
#include <hip/hip_bf16.h>
#include <math.h>

// ---------------------------------------------------------------------------
// MLA forward, bf16 MFMA + global_load_lds + balanced split-K attention.
// B=2 S=2048 H=2048 nh=16 hd=128 rd=64 L=256
// ---------------------------------------------------------------------------

typedef __attribute__((ext_vector_type(8))) short bf16x8;
typedef __attribute__((ext_vector_type(4))) float f32x4;
typedef unsigned int u32;

#define MFMA16(a, b, c) __builtin_amdgcn_mfma_f32_16x16x32_bf16(a, b, c, 0, 0, 0)

__device__ __forceinline__ short f2bs(float f) {
  __hip_bfloat16 h = __float2bfloat16(f);
  return *reinterpret_cast<short*>(&h);
}
__device__ __forceinline__ float bs2f(short s) {
  union { unsigned int u; float f; } v;
  v.u = ((unsigned int)(unsigned short)s) << 16;
  return v.f;
}
__device__ __forceinline__ u32 fbits(float f) {
  union { float f; u32 u; } v; v.f = f; return v.u;
}

// async global->LDS, 16B per lane (dest must be wave-uniform base + lane*16)
__device__ __forceinline__ void async16(const void* g, void* l) {
  __builtin_amdgcn_global_load_lds(
      (const __attribute__((address_space(1))) u32*)(unsigned long long)g,
      (__attribute__((address_space(3))) u32*)(unsigned int)(unsigned long long)l,
      16, 0, 0);
}
__device__ __forceinline__ void wait_vm0() {
  __builtin_amdgcn_s_waitcnt(0x0f70);  // vmcnt(0), lgkm/exp don't-care
}

// ---------------- cast fp32 -> bf16 (hs) ----------------
__global__ __launch_bounds__(256) void castf2b(const float* __restrict__ x,
                                               short* __restrict__ y) {
  int i = (blockIdx.x * 256 + threadIdx.x) * 4;
  float4 v = *(const float4*)(x + i);
  short4 o;
  o.x = f2bs(v.x); o.y = f2bs(v.y); o.z = f2bs(v.z); o.w = f2bs(v.w);
  *(short4*)(y + i) = o;
}

// ---------------- transpose + cast: W(K,N) f32 -> Wt slice (N rows, ld=K) --
__global__ __launch_bounds__(256) void wtrans(const float* __restrict__ W,
                                              short* __restrict__ Wt,
                                              int K, int N) {
  __shared__ float t[32][33];
  int k0 = blockIdx.y * 32, n0 = blockIdx.x * 32;
#pragma unroll
  for (int i = 0; i < 4; ++i) {
    int idx = threadIdx.x + i * 256;
    int r = idx >> 5, c = idx & 31;
    t[r][c] = W[(k0 + r) * N + n0 + c];
  }
  __syncthreads();
#pragma unroll
  for (int i = 0; i < 4; ++i) {
    int idx = threadIdx.x + i * 256;
    int r = idx >> 5, c = idx & 31;
    Wt[(n0 + r) * (size_t)K + k0 + c] = f2bs(t[c][r]);
  }
}

// ---------------- bf16 MFMA GEMM (m97-style): C = A @ Bt^T -----------------
__device__ __forceinline__ void cstore(float v, float* p) { *p = v; }
__device__ __forceinline__ void cstore(float v, short* p) { *p = f2bs(v); }

template <typename CT>
__global__ __launch_bounds__(256) void gemm_bt(const short* __restrict__ A, int lda,
                                               const short* __restrict__ Bt, int ldb,
                                               CT* __restrict__ C, int ldc, int K) {
  __shared__ short As[128 * 32];
  __shared__ short Bs[128 * 32];
  const int tid = threadIdx.x;
  const int wave = tid >> 6, lane = tid & 63;
  const int quad = lane >> 4, l15 = lane & 15;
  const int wm = wave & 1, wn = wave >> 1;
  const int row0 = blockIdx.y * 128, col0 = blockIdx.x * 128;
  const int ar = tid >> 2, ac = (tid & 3) * 8;
  const short* Ag = A + (size_t)(row0 + ar) * lda + ac;
  const short* Bg = Bt + (size_t)(col0 + ar) * ldb + ac;

  f32x4 acc[4][4];
#pragma unroll
  for (int i = 0; i < 4; ++i)
#pragma unroll
    for (int j = 0; j < 4; ++j) acc[i][j] = {0.f, 0.f, 0.f, 0.f};

  for (int k0 = 0; k0 < K; k0 += 32) {
    __syncthreads();
    async16(Ag + k0, &As[tid * 8]);
    async16(Ag + (size_t)64 * lda + k0, &As[2048 + tid * 8]);
    async16(Bg + k0, &Bs[tid * 8]);
    async16(Bg + (size_t)64 * ldb + k0, &Bs[2048 + tid * 8]);
    wait_vm0();
    __syncthreads();
    bf16x8 af[4], bfr[4];
#pragma unroll
    for (int i = 0; i < 4; ++i) {
      af[i]  = *(const bf16x8*)&As[(wm * 64 + i * 16 + l15) * 32 + quad * 8];
      bfr[i] = *(const bf16x8*)&Bs[(wn * 64 + i * 16 + l15) * 32 + quad * 8];
    }
#pragma unroll
    for (int i = 0; i < 4; ++i)
#pragma unroll
      for (int j = 0; j < 4; ++j)
        acc[i][j] = MFMA16(af[i], bfr[j], acc[i][j]);
  }
#pragma unroll
  for (int i = 0; i < 4; ++i)
#pragma unroll
    for (int j = 0; j < 4; ++j)
#pragma unroll
      for (int r = 0; r < 4; ++r) {
        int row = row0 + wm * 64 + i * 16 + quad * 4 + r;
        int col = col0 + wn * 64 + j * 16 + l15;
        cstore(acc[i][j][r], &C[(size_t)row * ldc + col]);
      }
}

// ---------------- RoPE + concat + head-major pack (bf16) -------------------
// qc/qr from C3 (ld 2048, qr at col 1024); kc from C2 (ld 3072); kr from C1
// (ld 1536, col 512). Q pre-scaled by 1/sqrt(128)*log2(e) for exp2 softmax.
__global__ __launch_bounds__(256) void rope_pack(
    const short* __restrict__ c3, const short* __restrict__ c2,
    const short* __restrict__ c1, short* __restrict__ qf,
    short* __restrict__ kf) {
  const float QSCALE = 0.08838834764831845f * 1.4426950408889634f;
  int idx = blockIdx.x * 256 + threadIdx.x;
  int m = idx >> 11;
  int col = idx & 2047;
  int h = col >> 7;
  int j = col & 127;
  int b = m >> 11, s = m & 2047;
  float oq, ok;
  if (j < 64) {
    oq = bs2f(c3[(size_t)m * 2048 + h * 64 + j]);          // q_c
    ok = bs2f(c2[(size_t)m * 3072 + h * 64 + j]);          // k_c
  } else {
    int jr = j - 64;
    int f = jr & 31;
    float ang = (float)s * __expf(-0.2878231366242557f * (float)f);
    float c = __cosf(ang), sn = __sinf(ang);
    size_t qb = (size_t)m * 2048 + 1024 + h * 64;          // q_r
    size_t kb = (size_t)m * 1536 + 512 + h * 64;           // k_r
    float xq = bs2f(c3[qb + jr]), xk = bs2f(c1[kb + jr]);
    float rq, rk;
    if (jr < 32) { rq = -bs2f(c3[qb + jr + 32]); rk = -bs2f(c1[kb + jr + 32]); }
    else         { rq =  bs2f(c3[qb + jr - 32]); rk =  bs2f(c1[kb + jr - 32]); }
    oq = fmaf(xq, c, rq * sn);
    ok = fmaf(xk, c, rk * sn);
  }
  size_t dst = (((size_t)b * 16 + h) * 2048 + s) * 128 + j;
  qf[dst] = f2bs(oq * QSCALE);
  kf[dst] = f2bs(ok);
}

// ---------------- V transpose: C2 col 1024 (ld 3072) -> vt(b,h,128,s) ------
__global__ __launch_bounds__(256) void vtrans(const short* __restrict__ c2,
                                              short* __restrict__ vt) {
  __shared__ short t[64][72];
  int s0 = blockIdx.x * 64, d0 = blockIdx.y * 64, bh = blockIdx.z;
  int b = bh >> 4, h = bh & 15;
#pragma unroll
  for (int i = 0; i < 16; ++i) {
    int idx = threadIdx.x + i * 256;
    int r = idx >> 6, c = idx & 63;
    t[r][c] = c2[(size_t)(b * 2048 + s0 + r) * 3072 + 1024 + h * 128 + d0 + c];
  }
  __syncthreads();
#pragma unroll
  for (int i = 0; i < 16; ++i) {
    int idx = threadIdx.x + i * 256;
    int r = idx >> 6, c = idx & 63;
    vt[((size_t)bh * 128 + d0 + r) * 2048 + s0 + c] = t[c][r];
  }
}

// ---------------- balanced split-K flash attention -------------------------
// Block x handles (qt=x, front k-half) then (qt=15-x, back k-half): 17 k-tiles
// each. 4 waves x 32 q-rows; transposed-S softmax; partial (O,m,l) out.
__global__ __launch_bounds__(256) void attn_split(const short* __restrict__ qf,
                                                  const short* __restrict__ kf,
                                                  const short* __restrict__ vt,
                                                  float* __restrict__ part,
                                                  float2* __restrict__ ml) {
  __shared__ short Ks[64 * 128];   // [kpos][d]
  __shared__ short Vs[128 * 64];   // [d][kpos]
  __shared__ short Pw[4][32 * 72]; // per-wave P [qrow][kpos], row stride 72
  const int x = blockIdx.x;
  const int bh = blockIdx.y;
  const int tid = threadIdx.x;
  const int wave = tid >> 6, lane = tid & 63;
  const int quad = lane >> 4, l15 = lane & 15;

  for (int pass = 0; pass < 2; ++pass) {
    const int qt = pass == 0 ? x : 15 - x;
    const int ks = pass == 0 ? 0 : qt + 1;
    const int ke = (qt + 1) << pass;        // front: qt+1, back: 2qt+2
    const int q0w = qt * 128 + wave * 32;

    bf16x8 qfr[2][4];
#pragma unroll
    for (int mi = 0; mi < 2; ++mi) {
      const short* qp = qf + (((size_t)bh * 2048) + q0w + mi * 16 + l15) * 128;
#pragma unroll
      for (int kc = 0; kc < 4; ++kc)
        qfr[mi][kc] = *(const bf16x8*)(qp + kc * 32 + quad * 8);
    }
    float m_i[2] = {-INFINITY, -INFINITY};
    float l_i[2] = {0.f, 0.f};
    f32x4 O[2][8];
#pragma unroll
    for (int mi = 0; mi < 2; ++mi)
#pragma unroll
      for (int dt = 0; dt < 8; ++dt) O[mi][dt] = {0.f, 0.f, 0.f, 0.f};

    for (int kt = ks; kt < ke; ++kt) {
      const int k0 = kt * 64;
      __syncthreads();
      {
        const short* kg = kf + (((size_t)bh * 2048) + k0 + (tid >> 4)) * 128 +
                          (tid & 15) * 8;
        const short* vg = vt + ((size_t)bh * 128 + (tid >> 3)) * 2048 + k0 +
                          (tid & 7) * 8;
#pragma unroll
        for (int i = 0; i < 4; ++i) {
          async16(kg + (size_t)i * 16 * 128, &Ks[i * 2048 + tid * 8]);
          async16(vg + (size_t)i * 32 * 2048, &Vs[i * 2048 + tid * 8]);
        }
      }
      wait_vm0();
      __syncthreads();

      // S^T = K @ Q^T  (m=kpos 64, n=qrow 32)
      f32x4 St[2][4];
#pragma unroll
      for (int mi = 0; mi < 2; ++mi)
#pragma unroll
        for (int j = 0; j < 4; ++j) St[mi][j] = {0.f, 0.f, 0.f, 0.f};
#pragma unroll
      for (int kc = 0; kc < 4; ++kc) {
        bf16x8 kb[4];
#pragma unroll
        for (int j = 0; j < 4; ++j)
          kb[j] = *(const bf16x8*)&Ks[(j * 16 + l15) * 128 + kc * 32 + quad * 8];
#pragma unroll
        for (int mi = 0; mi < 2; ++mi)
#pragma unroll
          for (int j = 0; j < 4; ++j)
            St[mi][j] = MFMA16(kb[j], qfr[mi][kc], St[mi][j]);
      }

      if (kt >= 2 * qt) {  // diagonal tiles: causal mask
#pragma unroll
        for (int mi = 0; mi < 2; ++mi)
#pragma unroll
          for (int j = 0; j < 4; ++j)
#pragma unroll
            for (int r = 0; r < 4; ++r)
              if (k0 + j * 16 + quad * 4 + r > q0w + mi * 16 + l15)
                St[mi][j][r] = -INFINITY;
      }

      float alpha[2];
#pragma unroll
      for (int mi = 0; mi < 2; ++mi) {
        float mt = -INFINITY;
#pragma unroll
        for (int j = 0; j < 4; ++j)
#pragma unroll
          for (int r = 0; r < 4; ++r) mt = fmaxf(mt, St[mi][j][r]);
        mt = fmaxf(mt, __shfl_xor(mt, 16));
        mt = fmaxf(mt, __shfl_xor(mt, 32));
        float mold = m_i[mi];
        float mnew = fmaxf(mold, mt);
        float msafe = (mnew == -INFINITY) ? 0.f : mnew;
        alpha[mi] = exp2f(mold - msafe);
        float ps = 0.f;
#pragma unroll
        for (int j = 0; j < 4; ++j)
#pragma unroll
          for (int r = 0; r < 4; ++r) {
            float p = exp2f(St[mi][j][r] - msafe);
            St[mi][j][r] = p;
            ps += p;
          }
        ps += __shfl_xor(ps, 16);
        ps += __shfl_xor(ps, 32);
        m_i[mi] = mnew;
        l_i[mi] = l_i[mi] * alpha[mi] + ps;
      }

      // P (truncated bf16) -> per-wave LDS, row-major [qrow][kpos]
#pragma unroll
      for (int mi = 0; mi < 2; ++mi)
#pragma unroll
        for (int j = 0; j < 4; ++j) {
          u32 u0 = (fbits(St[mi][j][1]) & 0xffff0000u) | (fbits(St[mi][j][0]) >> 16);
          u32 u1 = (fbits(St[mi][j][3]) & 0xffff0000u) | (fbits(St[mi][j][2]) >> 16);
          uint2 pk; pk.x = u0; pk.y = u1;
          *(uint2*)&Pw[wave][(mi * 16 + l15) * 72 + j * 16 + quad * 4] = pk;
        }

      // rescale O by alpha (broadcast to qrow = quad*4+r)
      float aB[2][4];
#pragma unroll
      for (int mi = 0; mi < 2; ++mi)
#pragma unroll
        for (int r = 0; r < 4; ++r)
          aB[mi][r] = __shfl(alpha[mi], quad * 4 + r, 16);
#pragma unroll
      for (int mi = 0; mi < 2; ++mi)
#pragma unroll
        for (int dt = 0; dt < 8; ++dt)
#pragma unroll
          for (int r = 0; r < 4; ++r) O[mi][dt][r] *= aB[mi][r];

      // O += P @ V
#pragma unroll
      for (int kc2 = 0; kc2 < 2; ++kc2) {
        bf16x8 pa[2];
#pragma unroll
        for (int mi = 0; mi < 2; ++mi)
          pa[mi] = *(const bf16x8*)&Pw[wave][(mi * 16 + l15) * 72 + kc2 * 32 + quad * 8];
#pragma unroll
        for (int dt = 0; dt < 8; ++dt) {
          bf16x8 vb = *(const bf16x8*)&Vs[(dt * 16 + l15) * 64 + kc2 * 32 + quad * 8];
#pragma unroll
          for (int mi = 0; mi < 2; ++mi)
            O[mi][dt] = MFMA16(pa[mi], vb, O[mi][dt]);
        }
      }
    }

    // store partial (O, m, l)
    const int pidx = (bh * 16 + qt) * 2 + pass;
    float* pb = part + (size_t)pidx * 128 * 128;
#pragma unroll
    for (int mi = 0; mi < 2; ++mi)
#pragma unroll
      for (int dt = 0; dt < 8; ++dt)
#pragma unroll
        for (int r = 0; r < 4; ++r)
          pb[(wave * 32 + mi * 16 + quad * 4 + r) * 128 + dt * 16 + l15] =
              O[mi][dt][r];
    if (quad == 0) {
#pragma unroll
      for (int mi = 0; mi < 2; ++mi) {
        float2 v; v.x = m_i[mi]; v.y = l_i[mi];
        ml[pidx * 128 + wave * 32 + mi * 16 + l15] = v;
      }
    }
  }
}

// ---------------- merge the two partials per q-tile ------------------------
__global__ __launch_bounds__(256) void attn_merge(const float* __restrict__ part,
                                                  const float2* __restrict__ ml,
                                                  short* __restrict__ y) {
  const int qt = blockIdx.x, bh = blockIdx.y;
  const int b = bh >> 4, h = bh & 15;
  const int d = threadIdx.x & 127, rh = threadIdx.x >> 7;
  const int p1 = (bh * 16 + qt) * 2, p2 = p1 + 1;
  for (int rr = 0; rr < 64; ++rr) {
    int row = rh * 64 + rr;
    float2 a = ml[p1 * 128 + row], c = ml[p2 * 128 + row];
    float m = fmaxf(a.x, c.x);
    float a1 = exp2f(a.x - m), a2 = exp2f(c.x - m);
    float l = a.y * a1 + c.y * a2;
    float o = (part[((size_t)p1 * 128 + row) * 128 + d] * a1 +
               part[((size_t)p2 * 128 + row) * 128 + d] * a2) / l;
    y[(((size_t)b * 2048 + qt * 128 + row) * 16 + h) * 128 + d] = f2bs(o);
  }
}

extern "C" void kernel_launch(void* const* d_in, const int* in_sizes, int n_in,
                              void* d_out, int out_size, void* d_ws, size_t ws_size,
                              hipStream_t stream) {
  const float* hs   = (const float*)d_in[0];
  const float* Wkvd = (const float*)d_in[1];
  const float* Wqd  = (const float*)d_in[2];
  const float* Wku  = (const float*)d_in[3];
  const float* Wqu  = (const float*)d_in[4];
  const float* Wvu  = (const float*)d_in[5];
  const float* Wrk  = (const float*)d_in[6];
  const float* Wrq  = (const float*)d_in[7];
  const float* Wo   = (const float*)d_in[8];
  float* out = (float*)d_out;
  char* ws = (char*)d_ws;
  const size_t MB = 1024ull * 1024ull;

  short* hs_b = (short*)(ws + 0 * MB);     // 16 MB
  short* W1t  = (short*)(ws + 16 * MB);    // (1536,2048) 6 MB: kvd|qd|rk ^T
  short* W2t  = (short*)(ws + 22 * MB);    // (3072,256) 1.5 MB: ku|vu ^T
  short* W3t  = (short*)(ws + 24 * MB);    // (2048,256) 1 MB: qu|rq ^T
  short* C1   = (short*)(ws + 25 * MB);    // (4096,1536): kv_d|q_d|k_r
  short* C2   = (short*)(ws + 37 * MB);    // (4096,3072): k_c|v
  short* C3   = (short*)(ws + 61 * MB);    // (4096,2048): q_c|q_r
  short* Wo_t = (short*)(ws + 77 * MB);    // (2048,2048) 8 MB
  short* q_f  = (short*)(ws + 85 * MB);    // (32,2048,128)
  short* k_f  = (short*)(ws + 101 * MB);
  short* v_t  = (short*)(ws + 117 * MB);   // (32,128,2048)
  short* y_b  = (short*)(ws + 133 * MB);   // (b,s,h,d) -> ends 149 MB
  // attention partials overlay dead prep buffers [0, 77 MB)
  float*  part = (float*)(ws + 0 * MB);    // 1024 x 128 x 128 f32 = 64 MB
  float2* mlb  = (float2*)(ws + 64 * MB);  // 1024 x 128 float2 = 1 MB

  dim3 blk(256);
  castf2b<<<dim3(8192), blk, 0, stream>>>(hs, hs_b);
  wtrans<<<dim3(8, 64),  blk, 0, stream>>>(Wkvd, W1t,                2048, 256);
  wtrans<<<dim3(8, 64),  blk, 0, stream>>>(Wqd,  W1t + 256 * 2048,   2048, 256);
  wtrans<<<dim3(32, 64), blk, 0, stream>>>(Wrk,  W1t + 512 * 2048,   2048, 1024);
  wtrans<<<dim3(32, 8),  blk, 0, stream>>>(Wku,  W2t,                256, 1024);
  wtrans<<<dim3(64, 8),  blk, 0, stream>>>(Wvu,  W2t + 1024 * 256,   256, 2048);
  wtrans<<<dim3(32, 8),  blk, 0, stream>>>(Wqu,  W3t,                256, 1024);
  wtrans<<<dim3(32, 8),  blk, 0, stream>>>(Wrq,  W3t + 1024 * 256,   256, 1024);
  wtrans<<<dim3(64, 64), blk, 0, stream>>>(Wo,   Wo_t,               2048, 2048);

  gemm_bt<short><<<dim3(12, 32), blk, 0, stream>>>(hs_b, 2048, W1t, 2048, C1, 1536, 2048);
  gemm_bt<short><<<dim3(24, 32), blk, 0, stream>>>(C1, 1536, W2t, 256, C2, 3072, 256);
  gemm_bt<short><<<dim3(16, 32), blk, 0, stream>>>(C1 + 256, 1536, W3t, 256, C3, 2048, 256);

  rope_pack<<<dim3(32768), blk, 0, stream>>>(C3, C2, C1, q_f, k_f);
  vtrans<<<dim3(32, 2, 32), blk, 0, stream>>>(C2, v_t);

  attn_split<<<dim3(16, 32), blk, 0, stream>>>(q_f, k_f, v_t, part, mlb);
  attn_merge<<<dim3(16, 32), blk, 0, stream>>>(part, mlb, y_b);

  gemm_bt<float><<<dim3(16, 32), blk, 0, stream>>>(y_b, 2048, Wo_t, 2048, out, 2048, 2048);
}

// Round 4
// 418.687 us; speedup vs baseline: 7.4015x; 1.0653x over previous
//
#include <hip/hip_runtime.h>
#include <hip/hip_bf16.h>
#include <math.h>

// ---------------------------------------------------------------------------
// MLA forward, bf16 MFMA + async staging with source-permuted XOR swizzle.
// B=2 S=2048 H=2048 nh=16 hd=128 rd=64 L=256
// ---------------------------------------------------------------------------

typedef __attribute__((ext_vector_type(8))) short bf16x8;
typedef __attribute__((ext_vector_type(4))) float f32x4;
typedef unsigned int u32;

#define MFMA16(a, b, c) __builtin_amdgcn_mfma_f32_16x16x32_bf16(a, b, c, 0, 0, 0)

__device__ __forceinline__ short f2bs(float f) {
  __hip_bfloat16 h = __float2bfloat16(f);
  return *reinterpret_cast<short*>(&h);
}
__device__ __forceinline__ float bs2f(short s) {
  union { unsigned int u; float f; } v;
  v.u = ((unsigned int)(unsigned short)s) << 16;
  return v.f;
}
__device__ __forceinline__ u32 fbits(float f) {
  union { float f; u32 u; } v; v.f = f; return v.u;
}

__device__ __forceinline__ void async16(const void* g, void* l) {
  __builtin_amdgcn_global_load_lds(
      (const __attribute__((address_space(1))) u32*)(unsigned long long)g,
      (__attribute__((address_space(3))) u32*)(unsigned int)(unsigned long long)l,
      16, 0, 0);
}
__device__ __forceinline__ void wait_vm0() {
  __builtin_amdgcn_s_waitcnt(0x0f70);  // vmcnt(0)
}

// ---------------- fused prep: cast hs + all weight transposes --------------
__device__ __forceinline__ void wtrans_tile(const float* __restrict__ W,
                                            short* __restrict__ Wt, int K, int N,
                                            int bx, int by, int tid) {
  __shared__ float t[32][33];
  int k0 = by * 32, n0 = bx * 32;
#pragma unroll
  for (int i = 0; i < 4; ++i) {
    int idx = tid + i * 256;
    int r = idx >> 5, c = idx & 31;
    t[r][c] = W[(size_t)(k0 + r) * N + n0 + c];
  }
  __syncthreads();
#pragma unroll
  for (int i = 0; i < 4; ++i) {
    int idx = tid + i * 256;
    int r = idx >> 5, c = idx & 31;
    Wt[(size_t)(n0 + r) * K + k0 + c] = f2bs(t[c][r]);
  }
}

__global__ __launch_bounds__(256) void prep_all(
    const float* __restrict__ hs, const float* __restrict__ Wkvd,
    const float* __restrict__ Wqd, const float* __restrict__ Wku,
    const float* __restrict__ Wqu, const float* __restrict__ Wvu,
    const float* __restrict__ Wrk, const float* __restrict__ Wrq,
    const float* __restrict__ Wo, short* __restrict__ hs_b,
    short* __restrict__ W1t, short* __restrict__ W2t,
    short* __restrict__ W3t, short* __restrict__ Wo_t) {
  const int b = blockIdx.x, tid = threadIdx.x;
  if (b < 8192) {  // cast hs -> bf16, 1024 elems/block
    int i = (b * 256 + tid) * 4;
    float4 v = *(const float4*)(hs + i);
    short4 o;
    o.x = f2bs(v.x); o.y = f2bs(v.y); o.z = f2bs(v.z); o.w = f2bs(v.w);
    *(short4*)(hs_b + i) = o;
  } else if (b < 8704) {        // Wkvd (2048,256)
    int l = b - 8192; wtrans_tile(Wkvd, W1t, 2048, 256, l & 7, l >> 3, tid);
  } else if (b < 9216) {        // Wqd
    int l = b - 8704; wtrans_tile(Wqd, W1t + 256 * 2048, 2048, 256, l & 7, l >> 3, tid);
  } else if (b < 11264) {       // Wrk (2048,1024)
    int l = b - 9216; wtrans_tile(Wrk, W1t + 512 * 2048, 2048, 1024, l & 31, l >> 5, tid);
  } else if (b < 11520) {       // Wku (256,1024)
    int l = b - 11264; wtrans_tile(Wku, W2t, 256, 1024, l & 31, l >> 5, tid);
  } else if (b < 12032) {       // Wvu (256,2048)
    int l = b - 11520; wtrans_tile(Wvu, W2t + 1024 * 256, 256, 2048, l & 63, l >> 6, tid);
  } else if (b < 12288) {       // Wqu (256,1024)
    int l = b - 12032; wtrans_tile(Wqu, W3t, 256, 1024, l & 31, l >> 5, tid);
  } else if (b < 12544) {       // Wrq (256,1024)
    int l = b - 12288; wtrans_tile(Wrq, W3t + 1024 * 256, 256, 1024, l & 31, l >> 5, tid);
  } else {                      // Wo (2048,2048)
    int l = b - 12544; wtrans_tile(Wo, Wo_t, 2048, 2048, l & 63, l >> 6, tid);
  }
}

// ---------------- bf16 MFMA GEMM, swizzled staging: C = A @ Bt^T -----------
__device__ __forceinline__ void cstore(float v, float* p) { *p = v; }
__device__ __forceinline__ void cstore(float v, short* p) { *p = f2bs(v); }

template <typename CT>
__global__ __launch_bounds__(256) void gemm_bt(const short* __restrict__ A, int lda,
                                               const short* __restrict__ Bt, int ldb,
                                               CT* __restrict__ C, int ldc, int K) {
  __shared__ short As[128 * 32];
  __shared__ short Bs[128 * 32];
  const int tid = threadIdx.x;
  const int wave = tid >> 6, lane = tid & 63;
  const int quad = lane >> 4, l15 = lane & 15;
  const int wm = wave & 1, wn = wave >> 1;
  const int row0 = blockIdx.y * 128, col0 = blockIdx.x * 128;
  // source-permuted swizzle: LDS slot (r,c) holds global chunk (r, c^ (r&3) ^ ((r>>2)&3))
  const int ar = tid >> 2;
  const int ac = (((tid & 3) ^ ((tid >> 2) & 3) ^ ((tid >> 4) & 3))) * 8;
  const short* Ag = A + (size_t)(row0 + ar) * lda + ac;
  const short* Bg = Bt + (size_t)(col0 + ar) * ldb + ac;
  const int sw = ((quad ^ (l15 & 3) ^ ((l15 >> 2) & 3))) * 8;

  f32x4 acc[4][4];
#pragma unroll
  for (int i = 0; i < 4; ++i)
#pragma unroll
    for (int j = 0; j < 4; ++j) acc[i][j] = {0.f, 0.f, 0.f, 0.f};

  for (int k0 = 0; k0 < K; k0 += 32) {
    __syncthreads();
    async16(Ag + k0, &As[tid * 8]);
    async16(Ag + (size_t)64 * lda + k0, &As[2048 + tid * 8]);
    async16(Bg + k0, &Bs[tid * 8]);
    async16(Bg + (size_t)64 * ldb + k0, &Bs[2048 + tid * 8]);
    wait_vm0();
    __syncthreads();
    bf16x8 af[4], bfr[4];
#pragma unroll
    for (int i = 0; i < 4; ++i) {
      af[i]  = *(const bf16x8*)&As[(wm * 64 + i * 16 + l15) * 32 + sw];
      bfr[i] = *(const bf16x8*)&Bs[(wn * 64 + i * 16 + l15) * 32 + sw];
    }
#pragma unroll
    for (int i = 0; i < 4; ++i)
#pragma unroll
      for (int j = 0; j < 4; ++j)
        acc[i][j] = MFMA16(af[i], bfr[j], acc[i][j]);
  }
#pragma unroll
  for (int i = 0; i < 4; ++i)
#pragma unroll
    for (int j = 0; j < 4; ++j)
#pragma unroll
      for (int r = 0; r < 4; ++r) {
        int row = row0 + wm * 64 + i * 16 + quad * 4 + r;
        int col = col0 + wn * 64 + j * 16 + l15;
        cstore(acc[i][j][r], &C[(size_t)row * ldc + col]);
      }
}

// ---------------- RoPE + concat + head-major pack (bf16) -------------------
__global__ __launch_bounds__(256) void rope_pack(
    const short* __restrict__ c3, const short* __restrict__ c2,
    const short* __restrict__ c1, short* __restrict__ qf,
    short* __restrict__ kf) {
  const float QSCALE = 0.08838834764831845f * 1.4426950408889634f;
  int idx = blockIdx.x * 256 + threadIdx.x;
  int m = idx >> 11;
  int col = idx & 2047;
  int h = col >> 7;
  int j = col & 127;
  int b = m >> 11, s = m & 2047;
  float oq, ok;
  if (j < 64) {
    oq = bs2f(c3[(size_t)m * 2048 + h * 64 + j]);
    ok = bs2f(c2[(size_t)m * 3072 + h * 64 + j]);
  } else {
    int jr = j - 64;
    int f = jr & 31;
    float ang = (float)s * __expf(-0.2878231366242557f * (float)f);
    float c = __cosf(ang), sn = __sinf(ang);
    size_t qb = (size_t)m * 2048 + 1024 + h * 64;
    size_t kb = (size_t)m * 1536 + 512 + h * 64;
    float xq = bs2f(c3[qb + jr]), xk = bs2f(c1[kb + jr]);
    float rq, rk;
    if (jr < 32) { rq = -bs2f(c3[qb + jr + 32]); rk = -bs2f(c1[kb + jr + 32]); }
    else         { rq =  bs2f(c3[qb + jr - 32]); rk =  bs2f(c1[kb + jr - 32]); }
    oq = fmaf(xq, c, rq * sn);
    ok = fmaf(xk, c, rk * sn);
  }
  size_t dst = (((size_t)b * 16 + h) * 2048 + s) * 128 + j;
  qf[dst] = f2bs(oq * QSCALE);
  kf[dst] = f2bs(ok);
}

// ---------------- V transpose: C2 col 1024 (ld 3072) -> vt(b,h,128,s) ------
__global__ __launch_bounds__(256) void vtrans(const short* __restrict__ c2,
                                              short* __restrict__ vt) {
  __shared__ short t[64][72];
  int s0 = blockIdx.x * 64, d0 = blockIdx.y * 64, bh = blockIdx.z;
  int b = bh >> 4, h = bh & 15;
#pragma unroll
  for (int i = 0; i < 16; ++i) {
    int idx = threadIdx.x + i * 256;
    int r = idx >> 6, c = idx & 63;
    t[r][c] = c2[(size_t)(b * 2048 + s0 + r) * 3072 + 1024 + h * 128 + d0 + c];
  }
  __syncthreads();
#pragma unroll
  for (int i = 0; i < 16; ++i) {
    int idx = threadIdx.x + i * 256;
    int r = idx >> 6, c = idx & 63;
    vt[((size_t)bh * 128 + d0 + r) * 2048 + s0 + c] = t[c][r];
  }
}

// ---------------- balanced split-K flash attention -------------------------
// Block x: (qt=x, front half) + (qt=15-x, back half) = 17 k-tiles. 4 waves x
// 32 q-rows. Transposed-S softmax; transposed PV (O^T: lane-col = q-row).
__global__ __launch_bounds__(256) void attn_split(const short* __restrict__ qf,
                                                  const short* __restrict__ kf,
                                                  const short* __restrict__ vt,
                                                  float* __restrict__ part,
                                                  float2* __restrict__ ml) {
  __shared__ short Ks[64 * 128];   // [kpos][d], chunk-swizzled c^=(r&15)
  __shared__ short Vs[128 * 64];   // [d][kpos], chunk-swizzled c^=(r&7)
  __shared__ short Pw[4][32 * 72]; // per-wave P [qrow][kpos], stride 72
  const int x = blockIdx.x;
  const int bh = blockIdx.y;
  const int tid = threadIdx.x;
  const int wave = tid >> 6, lane = tid & 63;
  const int quad = lane >> 4, l15 = lane & 15;
  // staging source addresses (swizzle folded into global column)
  const int krow_l = tid >> 4;                       // 0..15
  const int kcol_sw = ((tid & 15) ^ krow_l) * 8;
  const int vrow_l = tid >> 3;                       // 0..31
  const int vcol_sw = ((tid & 7) ^ (vrow_l & 7)) * 8;

  for (int pass = 0; pass < 2; ++pass) {
    const int qt = pass == 0 ? x : 15 - x;
    const int ks = pass == 0 ? 0 : qt + 1;
    const int ke = (qt + 1) << pass;
    const int q0w = qt * 128 + wave * 32;

    bf16x8 qfr[2][4];
#pragma unroll
    for (int mi = 0; mi < 2; ++mi) {
      const short* qp = qf + (((size_t)bh * 2048) + q0w + mi * 16 + l15) * 128;
#pragma unroll
      for (int kc = 0; kc < 4; ++kc)
        qfr[mi][kc] = *(const bf16x8*)(qp + kc * 32 + quad * 8);
    }
    float m_i[2] = {-INFINITY, -INFINITY};
    float l_i[2] = {0.f, 0.f};
    f32x4 O[2][8];  // O^T: [mi(q-col)][dt(d-rowtile)]
#pragma unroll
    for (int mi = 0; mi < 2; ++mi)
#pragma unroll
      for (int dt = 0; dt < 8; ++dt) O[mi][dt] = {0.f, 0.f, 0.f, 0.f};

    for (int kt = ks; kt < ke; ++kt) {
      const int k0 = kt * 64;
      __syncthreads();
      {
        const short* kg = kf + (((size_t)bh * 2048) + k0 + krow_l) * 128 + kcol_sw;
        const short* vg = vt + ((size_t)bh * 128 + vrow_l) * 2048 + k0 + vcol_sw;
#pragma unroll
        for (int i = 0; i < 4; ++i) {
          async16(kg + (size_t)i * 16 * 128, &Ks[i * 2048 + tid * 8]);
          async16(vg + (size_t)i * 32 * 2048, &Vs[i * 2048 + tid * 8]);
        }
      }
      wait_vm0();
      __syncthreads();

      // S^T = K @ Q^T  (m=kpos 64, n=qrow 32); lane col l15 = q-row
      f32x4 St[2][4];
#pragma unroll
      for (int mi = 0; mi < 2; ++mi)
#pragma unroll
        for (int j = 0; j < 4; ++j) St[mi][j] = {0.f, 0.f, 0.f, 0.f};
#pragma unroll
      for (int kc = 0; kc < 4; ++kc) {
        bf16x8 kb[4];
#pragma unroll
        for (int j = 0; j < 4; ++j)
          kb[j] = *(const bf16x8*)&Ks[(j * 16 + l15) * 128 +
                                      (((kc * 4 + quad) ^ l15) & 15) * 8];
#pragma unroll
        for (int mi = 0; mi < 2; ++mi)
#pragma unroll
          for (int j = 0; j < 4; ++j)
            St[mi][j] = MFMA16(kb[j], qfr[mi][kc], St[mi][j]);
      }

      if (kt >= 2 * qt) {  // diagonal: causal mask
#pragma unroll
        for (int mi = 0; mi < 2; ++mi)
#pragma unroll
          for (int j = 0; j < 4; ++j)
#pragma unroll
            for (int r = 0; r < 4; ++r)
              if (k0 + j * 16 + quad * 4 + r > q0w + mi * 16 + l15)
                St[mi][j][r] = -INFINITY;
      }

      float alpha[2];
#pragma unroll
      for (int mi = 0; mi < 2; ++mi) {
        float mt = -INFINITY;
#pragma unroll
        for (int j = 0; j < 4; ++j)
#pragma unroll
          for (int r = 0; r < 4; ++r) mt = fmaxf(mt, St[mi][j][r]);
        mt = fmaxf(mt, __shfl_xor(mt, 16));
        mt = fmaxf(mt, __shfl_xor(mt, 32));
        float mold = m_i[mi];
        float mnew = fmaxf(mold, mt);
        float msafe = (mnew == -INFINITY) ? 0.f : mnew;
        alpha[mi] = exp2f(mold - msafe);
        float ps = 0.f;
#pragma unroll
        for (int j = 0; j < 4; ++j)
#pragma unroll
          for (int r = 0; r < 4; ++r) {
            float p = exp2f(St[mi][j][r] - msafe);
            St[mi][j][r] = p;
            ps += p;
          }
        ps += __shfl_xor(ps, 16);
        ps += __shfl_xor(ps, 32);
        m_i[mi] = mnew;
        l_i[mi] = l_i[mi] * alpha[mi] + ps;
        // O^T rescale: lane col = q-row -> pure per-lane multiply
#pragma unroll
        for (int dt = 0; dt < 8; ++dt)
#pragma unroll
          for (int r = 0; r < 4; ++r) O[mi][dt][r] *= alpha[mi];
      }

      // P (truncated bf16) -> per-wave LDS, row-major [qrow][kpos]
#pragma unroll
      for (int mi = 0; mi < 2; ++mi)
#pragma unroll
        for (int j = 0; j < 4; ++j) {
          u32 u0 = (fbits(St[mi][j][1]) & 0xffff0000u) | (fbits(St[mi][j][0]) >> 16);
          u32 u1 = (fbits(St[mi][j][3]) & 0xffff0000u) | (fbits(St[mi][j][2]) >> 16);
          uint2 pk; pk.x = u0; pk.y = u1;
          *(uint2*)&Pw[wave][(mi * 16 + l15) * 72 + j * 16 + quad * 4] = pk;
        }

      // O^T += V^T-frag @ P-frag  (A: m=d from Vs, B: n=qrow from Pw)
#pragma unroll
      for (int kc2 = 0; kc2 < 2; ++kc2) {
        bf16x8 pa[2];
#pragma unroll
        for (int mi = 0; mi < 2; ++mi)
          pa[mi] = *(const bf16x8*)&Pw[wave][(mi * 16 + l15) * 72 + kc2 * 32 + quad * 8];
#pragma unroll
        for (int dt = 0; dt < 8; ++dt) {
          bf16x8 vb = *(const bf16x8*)&Vs[(dt * 16 + l15) * 64 +
                                          (((kc2 * 4 + quad) ^ (l15 & 7)) & 7) * 8];
#pragma unroll
          for (int mi = 0; mi < 2; ++mi)
            O[mi][dt] = MFMA16(vb, pa[mi], O[mi][dt]);
        }
      }
    }

    // store partial O (f32), vectorized: lane col = qrow, rows = d
    const int pidx = (bh * 16 + qt) * 2 + pass;
    float* pb = part + (size_t)pidx * 128 * 128;
#pragma unroll
    for (int mi = 0; mi < 2; ++mi) {
      int qrow = wave * 32 + mi * 16 + l15;
#pragma unroll
      for (int dt = 0; dt < 8; ++dt) {
        f32x4 vv = O[mi][dt];
        *(float4*)&pb[(size_t)qrow * 128 + dt * 16 + quad * 4] =
            *(float4*)&vv;
      }
    }
    if (quad == 0) {
#pragma unroll
      for (int mi = 0; mi < 2; ++mi) {
        float2 v; v.x = m_i[mi]; v.y = l_i[mi];
        ml[pidx * 128 + wave * 32 + mi * 16 + l15] = v;
      }
    }
  }
}

// ---------------- merge two partials per q-tile ----------------------------
__global__ __launch_bounds__(256) void attn_merge(const float* __restrict__ part,
                                                  const float2* __restrict__ ml,
                                                  short* __restrict__ y) {
  const int qt = blockIdx.x, bh = blockIdx.y;
  const int b = bh >> 4, h = bh & 15;
  const int row = threadIdx.x >> 1, d0 = (threadIdx.x & 1) * 64;
  const int p1 = (bh * 16 + qt) * 2, p2 = p1 + 1;
  float2 a = ml[p1 * 128 + row], c = ml[p2 * 128 + row];
  float m = fmaxf(a.x, c.x);
  float a1 = exp2f(a.x - m), a2 = exp2f(c.x - m);
  float invl = 1.f / (a.y * a1 + c.y * a2);
  a1 *= invl; a2 *= invl;
  const float* s1 = part + ((size_t)p1 * 128 + row) * 128 + d0;
  const float* s2 = part + ((size_t)p2 * 128 + row) * 128 + d0;
  short* yp = y + (((size_t)b * 2048 + qt * 128 + row) * 16 + h) * 128 + d0;
#pragma unroll
  for (int j = 0; j < 16; ++j) {
    float4 v1 = *(const float4*)(s1 + j * 4);
    float4 v2 = *(const float4*)(s2 + j * 4);
    short4 o;
    o.x = f2bs(v1.x * a1 + v2.x * a2);
    o.y = f2bs(v1.y * a1 + v2.y * a2);
    o.z = f2bs(v1.z * a1 + v2.z * a2);
    o.w = f2bs(v1.w * a1 + v2.w * a2);
    *(short4*)(yp + j * 4) = o;
  }
}

extern "C" void kernel_launch(void* const* d_in, const int* in_sizes, int n_in,
                              void* d_out, int out_size, void* d_ws, size_t ws_size,
                              hipStream_t stream) {
  const float* hs   = (const float*)d_in[0];
  const float* Wkvd = (const float*)d_in[1];
  const float* Wqd  = (const float*)d_in[2];
  const float* Wku  = (const float*)d_in[3];
  const float* Wqu  = (const float*)d_in[4];
  const float* Wvu  = (const float*)d_in[5];
  const float* Wrk  = (const float*)d_in[6];
  const float* Wrq  = (const float*)d_in[7];
  const float* Wo   = (const float*)d_in[8];
  float* out = (float*)d_out;
  char* ws = (char*)d_ws;
  const size_t MB = 1024ull * 1024ull;

  short* hs_b = (short*)(ws + 0 * MB);     // 16 MB
  short* W1t  = (short*)(ws + 16 * MB);    // (1536,2048): kvd|qd|rk ^T
  short* W2t  = (short*)(ws + 22 * MB);    // (3072,256): ku|vu ^T
  short* W3t  = (short*)(ws + 24 * MB);    // (2048,256): qu|rq ^T
  short* C1   = (short*)(ws + 25 * MB);    // (4096,1536): kv_d|q_d|k_r
  short* C2   = (short*)(ws + 37 * MB);    // (4096,3072): k_c|v
  short* C3   = (short*)(ws + 61 * MB);    // (4096,2048): q_c|q_r
  short* Wo_t = (short*)(ws + 77 * MB);    // (2048,2048)
  short* q_f  = (short*)(ws + 85 * MB);    // (32,2048,128)
  short* k_f  = (short*)(ws + 101 * MB);
  short* v_t  = (short*)(ws + 117 * MB);   // (32,128,2048)
  short* y_b  = (short*)(ws + 133 * MB);   // (b,s,h,d)
  float*  part = (float*)(ws + 0 * MB);    // overlay: 1024x128x128 f32 (64 MB)
  float2* mlb  = (float2*)(ws + 64 * MB);  // 1 MB

  dim3 blk(256);
  prep_all<<<dim3(16640), blk, 0, stream>>>(hs, Wkvd, Wqd, Wku, Wqu, Wvu, Wrk,
                                            Wrq, Wo, hs_b, W1t, W2t, W3t, Wo_t);

  gemm_bt<short><<<dim3(12, 32), blk, 0, stream>>>(hs_b, 2048, W1t, 2048, C1, 1536, 2048);
  gemm_bt<short><<<dim3(24, 32), blk, 0, stream>>>(C1, 1536, W2t, 256, C2, 3072, 256);
  gemm_bt<short><<<dim3(16, 32), blk, 0, stream>>>(C1 + 256, 1536, W3t, 256, C3, 2048, 256);

  rope_pack<<<dim3(32768), blk, 0, stream>>>(C3, C2, C1, q_f, k_f);
  vtrans<<<dim3(32, 2, 32), blk, 0, stream>>>(C2, v_t);

  attn_split<<<dim3(16, 32), blk, 0, stream>>>(q_f, k_f, v_t, part, mlb);
  attn_merge<<<dim3(16, 32), blk, 0, stream>>>(part, mlb, y_b);

  gemm_bt<float><<<dim3(16, 32), blk, 0, stream>>>(y_b, 2048, Wo_t, 2048, out, 2048, 2048);
}